// Round 14
// baseline (156.070 us; speedup 1.0000x reference)
//
#include <hip/hip_runtime.h>
#include <math.h>

// CapsNet dynamic routing — fp16-W streaming sweeps, (4b,4o) lane split.
//
// R13 post-mortem: R10 (512 blk) == R13 (768 blk) == ~44us -> LDS instruction
// port saturated: 16 broadcast ds_read_b128/row x ~12cyc = 46us ~= measured.
// R14: lane = (4 batches x 4 Dout) -> W 4 reads + x 4 reads = 8 LDS insts/row,
// all distinct-address (conflict-free; x via XOR-swizzled staging source).
// x joins W in the global_load_lds stream (5 ops/quad, counted vmcnt(5) --
// uniform FIFO avoids the ordering trap of mixing short/long-lived vm ops).
// bd reduce: 2x shfl_xor within 4-lane o-group. LDS 80KB/block -> 2 blocks/CU;
// VGPR budget <=128 (launch_bounds(512,4)) is exactly the 16-waves/CU band.
//
// x: [B=64, N=1152, Din=8], W: [C=128, N=1152, Din=8, Dout=16]
// out: [B=64, C=128, Dout=16]

typedef _Float16 half_t;
typedef _Float16 half2_t __attribute__((ext_vector_type(2)));
typedef float f4v __attribute__((ext_vector_type(4)));

constexpr int NCAP = 1152;
constexpr int DIN  = 8;
constexpr int DOUT = 16;
constexpr int NCLS = 128;
constexpr int NB   = 64;

constexpr int NW        = 8;                  // waves per sweep block
constexpr int SWEEP_BLK = NW * 64;            // 512 threads
constexpr int STG       = 4096;               // fp32 path: 4 bufs x 1KB per wave
constexpr int QSTRIDE   = 5120;               // fp16 path: 1KB W + 4KB x per quad
constexpr int CHQ       = 4;                  // fp16 path chunks -> 512 blocks

// ---------- fp16 path layout (float units) ----------
struct L16 {
    static constexpr size_t XSH_OFF = 0;                             // x fp16: [n][b] 16B
    static constexpr size_t XSH_SZ  = (size_t)NCAP * NB * 4;         // 294,912
    static constexpr size_t WH_OFF  = XSH_OFF + XSH_SZ;              // W fp16: 256B/row
    static constexpr size_t WH_SZ   = (size_t)NCLS * NCAP * 64;      // 9,437,184
    static constexpr size_t P1_OFF  = WH_OFF + WH_SZ;
    static constexpr size_t P1_SZ   = (size_t)NCLS * CHQ * DOUT * NB;
    static constexpr size_t P2_OFF  = P1_OFF + P1_SZ;
    static constexpr size_t P23_SZ  = (size_t)NCLS * CHQ * (DOUT + 1) * NB;
    static constexpr size_t P3_OFF  = P2_OFF + P23_SZ;
    static constexpr size_t VA_OFF  = P3_OFF + P23_SZ;
    static constexpr size_t V_SZ    = (size_t)NCLS * DOUT * NB;
    static constexpr size_t VB_OFF  = VA_OFF + V_SZ;
    static constexpr size_t TOTAL   = VB_OFF + V_SZ;
};

// ---------- fp32 fallback layout (R9) ----------
template<int CH> struct Layout {
    static constexpr size_t XS_OFF = 0;
    static constexpr size_t XS_SZ  = (size_t)NCAP * NB * DIN;
    static constexpr size_t P1_OFF = XS_OFF + XS_SZ;
    static constexpr size_t P1_SZ  = (size_t)NCLS * CH * DOUT * NB;
    static constexpr size_t P2_OFF = P1_OFF + P1_SZ;
    static constexpr size_t P23_SZ = (size_t)NCLS * CH * (DOUT + 1) * NB;
    static constexpr size_t P3_OFF = P2_OFF + P23_SZ;
    static constexpr size_t VA_OFF = P3_OFF + P23_SZ;
    static constexpr size_t V_SZ   = (size_t)NCLS * DOUT * NB;
    static constexpr size_t VB_OFF = VA_OFF + V_SZ;
    static constexpr size_t TOTAL  = VB_OFF + V_SZ;
};

#define WAITV(N) asm volatile("s_waitcnt vmcnt(" #N ")" ::: "memory")
#define SB() __builtin_amdgcn_sched_barrier(0)
#define AS1 __attribute__((address_space(1)))
#define AS3 __attribute__((address_space(3)))

__device__ __forceinline__ float fdot2(half2_t a, half2_t b, float c) {
#if __has_builtin(__builtin_amdgcn_fdot2)
    return __builtin_amdgcn_fdot2(a, b, c, false);
#else
    asm volatile("v_dot2_f32_f16 %0, %1, %2, %0" : "+v"(c) : "v"(a), "v"(b));
    return c;
#endif
}
__device__ __forceinline__ half2_t bch2(float f) { return __builtin_bit_cast(half2_t, f); }
__device__ __forceinline__ float bcf(half2_t h) { return __builtin_bit_cast(float, h); }

// ---- prep_x: squash(x), convert fp16, transpose to xsh[n][b] (4 half2 = 16B)
__global__ __launch_bounds__(256) void prep_x(const float* __restrict__ x,
                                              float* __restrict__ xsh) {
    const int g = blockIdx.x * 256 + threadIdx.x;   // g = n*64 + b
    const int n = g >> 6;
    const int b = g & 63;
    const float4* xp = reinterpret_cast<const float4*>(x + ((size_t)b * NCAP + n) * DIN);
    float4 a = xp[0], c4 = xp[1];
    float sq = a.x*a.x + a.y*a.y + a.z*a.z + a.w*a.w
             + c4.x*c4.x + c4.y*c4.y + c4.z*c4.z + c4.w*c4.w;
    float sc = sq / ((1.0f + sq) * sqrtf(sq));
    half2_t h0 = {(half_t)(a.x*sc),  (half_t)(a.y*sc)};
    half2_t h1 = {(half_t)(a.z*sc),  (half_t)(a.w*sc)};
    half2_t h2 = {(half_t)(c4.x*sc), (half_t)(c4.y*sc)};
    half2_t h3 = {(half_t)(c4.z*sc), (half_t)(c4.w*sc)};
    float4 o;
    o.x = bcf(h0); o.y = bcf(h1); o.z = bcf(h2); o.w = bcf(h3);
    reinterpret_cast<float4*>(xsh)[g] = o;
}

// ---- prep_w: W row (c,n) -> fp16 half2 pairs, layout [ip][o], 256B/row.
__global__ __launch_bounds__(256) void prep_w(const float* __restrict__ W,
                                              float* __restrict__ wh) {
    const int g   = blockIdx.x * 256 + threadIdx.x;
    const int row = g >> 2;
    const int ip  = g & 3;
    const float4* src = reinterpret_cast<const float4*>(W + (size_t)row * 128 + ip * 32);
    float4 a0 = src[0], a1 = src[1], a2 = src[2], a3 = src[3];   // W[2ip][0..15]
    float4 b0 = src[4], b1 = src[5], b2 = src[6], b3 = src[7];   // W[2ip+1][0..15]
    const float f0[16] = {a0.x,a0.y,a0.z,a0.w, a1.x,a1.y,a1.z,a1.w,
                          a2.x,a2.y,a2.z,a2.w, a3.x,a3.y,a3.z,a3.w};
    const float f1[16] = {b0.x,b0.y,b0.z,b0.w, b1.x,b1.y,b1.z,b1.w,
                          b2.x,b2.y,b2.z,b2.w, b3.x,b3.y,b3.z,b3.w};
    float4 d[4];
#pragma unroll
    for (int j = 0; j < 4; ++j) {
        half2_t h0 = {(half_t)f0[4*j+0], (half_t)f1[4*j+0]};
        half2_t h1 = {(half_t)f0[4*j+1], (half_t)f1[4*j+1]};
        half2_t h2 = {(half_t)f0[4*j+2], (half_t)f1[4*j+2]};
        half2_t h3 = {(half_t)f0[4*j+3], (half_t)f1[4*j+3]};
        d[j].x = bcf(h0); d[j].y = bcf(h1); d[j].z = bcf(h2); d[j].w = bcf(h3);
    }
    float4* dst = reinterpret_cast<float4*>(wh + (size_t)row * 64 + ip * 16);
    dst[0] = d[0]; dst[1] = d[1]; dst[2] = d[2]; dst[3] = d[3];
}

// ---- fp16 sweep, (4b,4o) lane split. Quad = 4 rows; staged as 1KB W + 4KB x.
template<bool WEIGHTED, int CH>
__global__ __launch_bounds__(SWEEP_BLK, 4) void sweep_q(const float* __restrict__ xsh,
                                                        const float* __restrict__ wh,
                                                        float* __restrict__ P,
                                                        const float* __restrict__ vbuf) {
    constexpr int NPC = NCAP / CH;      // 288 rows per block
    constexpr int NPW = NPC / NW;       // 36 rows per wave
    constexpr int NPQ = NPW / 4;        // 9 quads per wave
    static_assert(NPW * NW == NPC && NPQ * 4 == NPW, "geometry");

    const int bg_ = blockIdx.x;          // = c*CH + ch
    const int c   = bg_ / CH;
    const int ch  = bg_ % CH;
    const int lane = threadIdx.x & 63;
    const int w    = threadIdx.x >> 6;
    const int oq   = lane & 3;           // o-quarter: o = oq*4..oq*4+3
    const int bg   = lane >> 2;          // batch group: b = bg*4..bg*4+3

    // per-wave: 2-quad ring x (1KB W + 4KB x) = 10KB; total 80KB (union w/ red)
    __shared__ __align__(16) char smem[NW * 2 * QSTRIDE];

    // V (weighted): Vf[j][k] = V[c][oq*4+k][bg*4+j]
    float Vf[4][4];
    if (WEIGHTED) {
        const float* vb = vbuf + (size_t)c * DOUT * NB;
#pragma unroll
        for (int j = 0; j < 4; ++j)
#pragma unroll
            for (int k = 0; k < 4; ++k)
                Vf[j][k] = vb[(oq * 4 + k) * NB + bg * 4 + j];
    }
    WAITV(0);   // drain V loads so the vm FIFO is clean for counted staging

    float S[4][4];
#pragma unroll
    for (int j = 0; j < 4; ++j)
#pragma unroll
        for (int k = 0; k < 4; ++k) S[j][k] = 0.f;
    float Zr[4] = {0.f, 0.f, 0.f, 0.f};

    const int n0 = ch * NPC + w * NPW;
    const char* wsrc = (const char*)wh + ((size_t)c * NCAP + n0) * 256;
    const char* xsrc = (const char*)xsh + (size_t)n0 * 1024;
    char* mybuf = smem + w * (2 * QSTRIDE);

    // x staging source swizzle (involution): slot L holds batch L^(L>>3).
    const int xl = lane ^ (lane >> 3);
    int xpos[4];
#pragma unroll
    for (int j = 0; j < 4; ++j) {
        const int b = bg * 4 + j;
        xpos[j] = b ^ (b >> 3);
    }

    auto STAGEQ = [&](int q) {   // 5 vm ops: W(1KB) + 4 x rows (1KB each)
        char* dst = mybuf + (q & 1) * QSTRIDE;
        __builtin_amdgcn_global_load_lds(
            (const AS1 void*)(wsrc + (size_t)q * 1024 + lane * 16),
            (AS3 void*)(dst), 16, 0, 0);
#pragma unroll
        for (int r = 0; r < 4; ++r) {
            __builtin_amdgcn_global_load_lds(
                (const AS1 void*)(xsrc + (size_t)(4 * q + r) * 1024 + xl * 16),
                (AS3 void*)(dst + 1024 + r * 1024), 16, 0, 0);
        }
    };

    auto ROWF = [&](int q, int r) {
        const char* buf  = mybuf + (q & 1) * QSTRIDE;
        const char* wrow = buf + r * 256 + oq * 16;
        f4v wip[4];
#pragma unroll
        for (int ip = 0; ip < 4; ++ip)
            wip[ip] = *reinterpret_cast<const f4v*>(wrow + ip * 64);
        const char* xq = buf + 1024 + r * 1024;
        f4v xb[4];
#pragma unroll
        for (int j = 0; j < 4; ++j)
            xb[j] = *reinterpret_cast<const f4v*>(xq + xpos[j] * 16);

        if (!WEIGHTED) {
#pragma unroll
            for (int ip = 0; ip < 4; ++ip)
#pragma unroll
                for (int j = 0; j < 4; ++j) {
                    const half2_t xj = bch2(xb[j][ip]);
#pragma unroll
                    for (int k = 0; k < 4; ++k)
                        S[j][k] = fdot2(xj, bch2(wip[ip][k]), S[j][k]);
                }
        } else {
            float u[4][4];
#pragma unroll
            for (int j = 0; j < 4; ++j)
#pragma unroll
                for (int k = 0; k < 4; ++k) u[j][k] = 0.f;
#pragma unroll
            for (int ip = 0; ip < 4; ++ip)
#pragma unroll
                for (int j = 0; j < 4; ++j) {
                    const half2_t xj = bch2(xb[j][ip]);
#pragma unroll
                    for (int k = 0; k < 4; ++k)
                        u[j][k] = fdot2(xj, bch2(wip[ip][k]), u[j][k]);
                }
            float bdp[4];
#pragma unroll
            for (int j = 0; j < 4; ++j) {
                float t = u[j][0] * Vf[j][0];
                t = fmaf(u[j][1], Vf[j][1], t);
                t = fmaf(u[j][2], Vf[j][2], t);
                t = fmaf(u[j][3], Vf[j][3], t);
                bdp[j] = t;
            }
#pragma unroll
            for (int j = 0; j < 4; ++j) bdp[j] += __shfl_xor(bdp[j], 1);
#pragma unroll
            for (int j = 0; j < 4; ++j) bdp[j] += __shfl_xor(bdp[j], 2);
#pragma unroll
            for (int j = 0; j < 4; ++j) {
                const float g = __expf(bdp[j]);   // |bd| <= ~48, fp32-safe
                Zr[j] += g;
#pragma unroll
                for (int k = 0; k < 4; ++k)
                    S[j][k] = fmaf(g, u[j][k], S[j][k]);
            }
        }
    };

    // ---- pipeline: quad q+1 staged while computing quad q. vmcnt(5) steady.
    STAGEQ(0);
#pragma unroll 1
    for (int q = 0; q < NPQ; ++q) {
        if (q + 1 < NPQ) { STAGEQ(q + 1); SB(); WAITV(5); SB(); }
        else             { SB(); WAITV(0); SB(); }
        ROWF(q, 0); ROWF(q, 1); ROWF(q, 2); ROWF(q, 3);
    }

    // ---- cross-wave merge (reuse smem after staging consumed)
    __syncthreads();
    float (*red)[DOUT + 1][NB] = reinterpret_cast<float (*)[DOUT + 1][NB]>(smem);
#pragma unroll
    for (int j = 0; j < 4; ++j)
#pragma unroll
        for (int k = 0; k < 4; ++k)
            red[w][oq * 4 + k][bg * 4 + j] = S[j][k];
    if (WEIGHTED) {
        if (oq == 0) {
#pragma unroll
            for (int j = 0; j < 4; ++j) red[w][DOUT][bg * 4 + j] = Zr[j];
        }
    }
    __syncthreads();
    for (int idx = threadIdx.x; idx < (DOUT + 1) * NB; idx += SWEEP_BLK) {
        const int slot = idx >> 6;
        const int bb   = idx & 63;
        float acc = 0.f;
#pragma unroll
        for (int k = 0; k < NW; ++k) acc += red[k][slot][bb];
        if (!WEIGHTED) {
            if (slot < DOUT)
                P[((size_t)bg_ * DOUT + slot) * NB + bb] = acc;
        } else {
            P[((size_t)bg_ * (DOUT + 1) + slot) * NB + bb] = acc;
        }
    }
}

// ================= fp32 fallback path (R9, proven) =================
__global__ __launch_bounds__(256) void prep_kernel(const float* __restrict__ x,
                                                   float* __restrict__ xs) {
    const int g = blockIdx.x * 256 + threadIdx.x;
    const int n = g >> 6;
    const int b = g & 63;
    const float4* xp = reinterpret_cast<const float4*>(x + ((size_t)b * NCAP + n) * DIN);
    float4 a = xp[0], c4 = xp[1];
    float sq = a.x*a.x + a.y*a.y + a.z*a.z + a.w*a.w
             + c4.x*c4.x + c4.y*c4.y + c4.z*c4.z + c4.w*c4.w;
    float sc = sq / ((1.0f + sq) * sqrtf(sq));
    float4 o0 = {a.x*sc,  a.y*sc,  a.z*sc,  a.w*sc};
    float4 o1 = {c4.x*sc, c4.y*sc, c4.z*sc, c4.w*sc};
    float4* op = reinterpret_cast<float4*>(xs + (size_t)g * DIN);
    op[0] = o0;
    op[1] = o1;
}

template<bool WEIGHTED, int CH>
__global__ __launch_bounds__(SWEEP_BLK, 2) void sweep_kernel(const float* __restrict__ xs,
                                                             const float* __restrict__ W,
                                                             float* __restrict__ P,
                                                             const float* __restrict__ vbuf) {
    constexpr int NPC    = NCAP / CH;
    constexpr int NPW    = NPC / NW;
    constexpr int NPAIRS = NPW / 2;

    const int bg = blockIdx.x;
    const int c  = bg / CH;
    const int ch = bg % CH;
    const int b  = threadIdx.x & 63;
    const int w  = threadIdx.x >> 6;

    __shared__ __align__(16) char smem[NW * (DOUT + 1) * NB * 4];

    float V[DOUT];
    if (WEIGHTED) {
        const float* vb = vbuf + (size_t)c * DOUT * NB + b;
#pragma unroll
        for (int o = 0; o < DOUT; ++o) V[o] = vb[o * NB];
    }

    float S[DOUT];
#pragma unroll
    for (int o = 0; o < DOUT; ++o) S[o] = 0.f;
    float Z = 0.f;

    const int n0 = ch * NPC + w * NPW;
    const char* wsrc = (const char*)W + ((size_t)c * NCAP + n0) * 512;
    char* mybuf = smem + w * STG;

    auto STAGE = [&](int p) {
        __builtin_amdgcn_global_load_lds(
            (const AS1 void*)(wsrc + (size_t)p * 1024 + b * 16),
            (AS3 void*)(mybuf + (p & 3) * 1024), 16, 0, 0);
    };
    auto XROW = [&](int row, float4& xa, float4& xb) {
        const float4* xp = reinterpret_cast<const float4*>(
            xs + ((size_t)(n0 + row) * NB + b) * DIN);
        xa = xp[0];
        xb = xp[1];
    };
    auto ROW = [&](int p, int r, float4 xa, float4 xb) {
        const float4* wl = reinterpret_cast<const float4*>(mybuf + (p & 3) * 1024 + r * 512);
        const float xv[DIN] = {xa.x, xa.y, xa.z, xa.w, xb.x, xb.y, xb.z, xb.w};
        if (!WEIGHTED) {
#pragma unroll
            for (int i = 0; i < DIN; ++i) {
                float4 q0 = wl[i*4+0], q1 = wl[i*4+1], q2 = wl[i*4+2], q3 = wl[i*4+3];
                const float xi = xv[i];
                S[ 0]=fmaf(xi,q0.x,S[ 0]); S[ 1]=fmaf(xi,q0.y,S[ 1]);
                S[ 2]=fmaf(xi,q0.z,S[ 2]); S[ 3]=fmaf(xi,q0.w,S[ 3]);
                S[ 4]=fmaf(xi,q1.x,S[ 4]); S[ 5]=fmaf(xi,q1.y,S[ 5]);
                S[ 6]=fmaf(xi,q1.z,S[ 6]); S[ 7]=fmaf(xi,q1.w,S[ 7]);
                S[ 8]=fmaf(xi,q2.x,S[ 8]); S[ 9]=fmaf(xi,q2.y,S[ 9]);
                S[10]=fmaf(xi,q2.z,S[10]); S[11]=fmaf(xi,q2.w,S[11]);
                S[12]=fmaf(xi,q3.x,S[12]); S[13]=fmaf(xi,q3.y,S[13]);
                S[14]=fmaf(xi,q3.z,S[14]); S[15]=fmaf(xi,q3.w,S[15]);
            }
        } else {
            float u[DOUT];
#pragma unroll
            for (int o = 0; o < DOUT; ++o) u[o] = 0.f;
#pragma unroll
            for (int i = 0; i < DIN; ++i) {
                float4 q0 = wl[i*4+0], q1 = wl[i*4+1], q2 = wl[i*4+2], q3 = wl[i*4+3];
                const float xi = xv[i];
                u[ 0]=fmaf(xi,q0.x,u[ 0]); u[ 1]=fmaf(xi,q0.y,u[ 1]);
                u[ 2]=fmaf(xi,q0.z,u[ 2]); u[ 3]=fmaf(xi,q0.w,u[ 3]);
                u[ 4]=fmaf(xi,q1.x,u[ 4]); u[ 5]=fmaf(xi,q1.y,u[ 5]);
                u[ 6]=fmaf(xi,q1.z,u[ 6]); u[ 7]=fmaf(xi,q1.w,u[ 7]);
                u[ 8]=fmaf(xi,q2.x,u[ 8]); u[ 9]=fmaf(xi,q2.y,u[ 9]);
                u[10]=fmaf(xi,q2.z,u[10]); u[11]=fmaf(xi,q2.w,u[11]);
                u[12]=fmaf(xi,q3.x,u[12]); u[13]=fmaf(xi,q3.y,u[13]);
                u[14]=fmaf(xi,q3.z,u[14]); u[15]=fmaf(xi,q3.w,u[15]);
            }
            float bd = 0.f;
#pragma unroll
            for (int o = 0; o < DOUT; ++o) bd = fmaf(u[o], V[o], bd);
            const float g = __expf(bd);
            Z += g;
#pragma unroll
            for (int o = 0; o < DOUT; ++o) S[o] = fmaf(g, u[o], S[o]);
        }
    };

    STAGE(0); SB();
    STAGE(1); SB();
    float4 ca0, ca1, cb0, cb1, na0, na1, nb0, nb1;
    XROW(0, ca0, ca1);
    XROW(1, cb0, cb1);
    SB();

#pragma unroll 1
    for (int p = 0; p < NPAIRS; ++p) {
        if (p + 2 < NPAIRS) STAGE(p + 2);
        SB();
        if (p + 1 < NPAIRS) {
            XROW(2 * (p + 1),     na0, na1);
            XROW(2 * (p + 1) + 1, nb0, nb1);
        }
        SB();
        if (p < NPAIRS - 2)       { WAITV(5); }
        else if (p == NPAIRS - 2) { WAITV(4); }
        else                      { WAITV(0); }
        SB();
        ROW(p, 0, ca0, ca1);
        ROW(p, 1, cb0, cb1);
        ca0 = na0; ca1 = na1; cb0 = nb0; cb1 = nb1;
    }

    __syncthreads();
    float (*red)[DOUT + 1][NB] = reinterpret_cast<float (*)[DOUT + 1][NB]>(smem);
#pragma unroll
    for (int o = 0; o < DOUT; ++o) red[w][o][b] = S[o];
    red[w][DOUT][b] = Z;
    __syncthreads();
    for (int idx = threadIdx.x; idx < (DOUT + 1) * NB; idx += SWEEP_BLK) {
        const int slot = idx >> 6;
        const int bb   = idx & 63;
        float acc = 0.f;
#pragma unroll
        for (int k = 0; k < NW; ++k) acc += red[k][slot][bb];
        if (!WEIGHTED) {
            if (slot < DOUT)
                P[((size_t)bg * DOUT + slot) * NB + bb] = acc;
        } else {
            P[((size_t)bg * (DOUT + 1) + slot) * NB + bb] = acc;
        }
    }
}

// ---- vupd: merge partials -> V. MODE1: squash(sum/N). MODE2: vin + squash(S/Z).
template<int MODE, int CH>
__global__ __launch_bounds__(64) void vupd_kernel(const float* __restrict__ P,
                                                  const float* __restrict__ vin,
                                                  float* __restrict__ vout) {
    const int c = blockIdx.x;
    const int b = threadIdx.x;

    float s[DOUT];
    float sq = 0.f;
    if (MODE == 1) {
#pragma unroll
        for (int o = 0; o < DOUT; ++o) {
            float acc = 0.f;
#pragma unroll
            for (int k = 0; k < CH; ++k)
                acc += P[(((size_t)c * CH + k) * DOUT + o) * NB + b];
            acc *= (1.0f / (float)NCAP);
            s[o] = acc;
            sq += acc * acc;
        }
    } else {
        float Zt = 0.f;
#pragma unroll
        for (int k = 0; k < CH; ++k)
            Zt += P[(((size_t)c * CH + k) * (DOUT + 1) + DOUT) * NB + b];
        const float rz = 1.0f / Zt;
#pragma unroll
        for (int o = 0; o < DOUT; ++o) {
            float acc = 0.f;
#pragma unroll
            for (int k = 0; k < CH; ++k)
                acc += P[(((size_t)c * CH + k) * (DOUT + 1) + o) * NB + b];
            acc *= rz;
            s[o] = acc;
            sq += acc * acc;
        }
    }
    const float sc = sq / ((1.0f + sq) * sqrtf(sq));
#pragma unroll
    for (int o = 0; o < DOUT; ++o) {
        float v = s[o] * sc;
        if (MODE == 2) v += vin[((size_t)c * DOUT + o) * NB + b];
        vout[((size_t)c * DOUT + o) * NB + b] = v;
    }
}

// ---- final: merge P3 -> v3, leaky^2, per-batch normalize
template<int CH>
__global__ __launch_bounds__(256) void final_kernel(const float* __restrict__ P3,
                                                    float* __restrict__ out) {
    const int b    = blockIdx.x;
    const int tid  = threadIdx.x;
    const int c    = tid >> 1;
    const int half = tid & 1;

    float Zt = 0.f;
#pragma unroll
    for (int k = 0; k < CH; ++k)
        Zt += P3[(((size_t)c * CH + k) * (DOUT + 1) + DOUT) * NB + b];
    const float rz = 1.0f / Zt;

    float s[8];
    float sqh = 0.f;
#pragma unroll
    for (int j = 0; j < 8; ++j) {
        const int o = half * 8 + j;
        float acc = 0.f;
#pragma unroll
        for (int k = 0; k < CH; ++k)
            acc += P3[(((size_t)c * CH + k) * (DOUT + 1) + o) * NB + b];
        acc *= rz;
        s[j] = acc;
        sqh += acc * acc;
    }
    const float sq = sqh + __shfl_xor(sqh, 1);
    const float sc = sq / ((1.0f + sq) * sqrtf(sq));

    float val[8];
    float ps = 0.f;
#pragma unroll
    for (int j = 0; j < 8; ++j) {
        const float v = s[j] * sc;
        const float l = v > 0.f ? v : 0.01f * v;
        val[j] = l * l;
        ps += val[j];
    }
#pragma unroll
    for (int off = 1; off < 64; off <<= 1) ps += __shfl_xor(ps, off);
    __shared__ float wsum[4];
    if ((tid & 63) == 0) wsum[tid >> 6] = ps;
    __syncthreads();
    const float inv = 1.0f / (wsum[0] + wsum[1] + wsum[2] + wsum[3]);
#pragma unroll
    for (int j = 0; j < 8; ++j)
        out[((size_t)b * NCLS + c) * DOUT + half * 8 + j] = val[j] * inv;
}

template<int CH>
static void run_f32(const float* x, const float* W, float* out, float* ws,
                    hipStream_t stream) {
    using L = Layout<CH>;
    float* xs = ws + L::XS_OFF;
    float* P1 = ws + L::P1_OFF;
    float* P2 = ws + L::P2_OFF;
    float* P3 = ws + L::P3_OFF;
    float* VA = ws + L::VA_OFF;
    float* VB = ws + L::VB_OFF;

    hipLaunchKernelGGL(prep_kernel, dim3(NCAP * NB / 256), dim3(256), 0, stream, x, xs);
    hipLaunchKernelGGL((sweep_kernel<false, CH>), dim3(NCLS * CH), dim3(SWEEP_BLK), 0,
                       stream, xs, W, P1, nullptr);
    hipLaunchKernelGGL((vupd_kernel<1, CH>), dim3(NCLS), dim3(64), 0, stream,
                       P1, nullptr, VA);
    hipLaunchKernelGGL((sweep_kernel<true, CH>), dim3(NCLS * CH), dim3(SWEEP_BLK), 0,
                       stream, xs, W, P2, VA);
    hipLaunchKernelGGL((vupd_kernel<2, CH>), dim3(NCLS), dim3(64), 0, stream,
                       P2, VA, VB);
    hipLaunchKernelGGL((sweep_kernel<true, CH>), dim3(NCLS * CH), dim3(SWEEP_BLK), 0,
                       stream, xs, W, P3, VB);
    hipLaunchKernelGGL((final_kernel<CH>), dim3(NB), dim3(256), 0, stream, P3, out);
}

extern "C" void kernel_launch(void* const* d_in, const int* in_sizes, int n_in,
                              void* d_out, int out_size, void* d_ws, size_t ws_size,
                              hipStream_t stream) {
    const float* x = (const float*)d_in[0];
    const float* W = (const float*)d_in[1];
    float* out = (float*)d_out;
    float* ws  = (float*)d_ws;

    if (ws_size >= L16::TOTAL * sizeof(float)) {
        float* xsh = ws + L16::XSH_OFF;
        float* wh  = ws + L16::WH_OFF;
        float* P1  = ws + L16::P1_OFF;
        float* P2  = ws + L16::P2_OFF;
        float* P3  = ws + L16::P3_OFF;
        float* VA  = ws + L16::VA_OFF;
        float* VB  = ws + L16::VB_OFF;

        hipLaunchKernelGGL(prep_x, dim3(NCAP * NB / 256), dim3(256), 0, stream, x, xsh);
        hipLaunchKernelGGL(prep_w, dim3(NCLS * NCAP * 4 / 256), dim3(256), 0, stream, W, wh);
        hipLaunchKernelGGL((sweep_q<false, CHQ>), dim3(NCLS * CHQ), dim3(SWEEP_BLK), 0,
                           stream, xsh, wh, P1, nullptr);
        hipLaunchKernelGGL((vupd_kernel<1, CHQ>), dim3(NCLS), dim3(64), 0, stream,
                           P1, nullptr, VA);
        hipLaunchKernelGGL((sweep_q<true, CHQ>), dim3(NCLS * CHQ), dim3(SWEEP_BLK), 0,
                           stream, xsh, wh, P2, VA);
        hipLaunchKernelGGL((vupd_kernel<2, CHQ>), dim3(NCLS), dim3(64), 0, stream,
                           P2, VA, VB);
        hipLaunchKernelGGL((sweep_q<true, CHQ>), dim3(NCLS * CHQ), dim3(SWEEP_BLK), 0,
                           stream, xsh, wh, P3, VB);
        hipLaunchKernelGGL((final_kernel<CHQ>), dim3(NB), dim3(256), 0, stream, P3, out);
    } else if (ws_size >= Layout<8>::TOTAL * sizeof(float)) {
        run_f32<8>(x, W, out, ws, stream);
    } else {
        run_f32<4>(x, W, out, ws, stream);
    }
}

// Round 15
// 150.170 us; speedup vs baseline: 1.0393x; 1.0393x over previous
//
#include <hip/hip_runtime.h>
#include <math.h>

// CapsNet dynamic routing — fp16-W streaming sweeps, (4b,4o) lane split + DPP.
//
// R14 post-mortem: __shfl_xor = ds_bpermute = LDS-port op -> 16 LDS ops/row,
// same as R13 (whose time exactly matches the LDS-pipe model: 576 rows/CU x
// 16 x 11.5cy = 44us). R15: ONE change — the 4-lane bd reduction uses DPP
// quad_perm adds (VALU, ctrl 0xB1=xor1, 0x4E=xor2) instead of shfl. LDS
// ops/row: 16 -> 8 (4 W + 4 x ds_read_b128). Everything else = R14.
//
// x: [B=64, N=1152, Din=8], W: [C=128, N=1152, Din=8, Dout=16]
// out: [B=64, C=128, Dout=16]

typedef _Float16 half_t;
typedef _Float16 half2_t __attribute__((ext_vector_type(2)));
typedef float f4v __attribute__((ext_vector_type(4)));

constexpr int NCAP = 1152;
constexpr int DIN  = 8;
constexpr int DOUT = 16;
constexpr int NCLS = 128;
constexpr int NB   = 64;

constexpr int NW        = 8;                  // waves per sweep block
constexpr int SWEEP_BLK = NW * 64;            // 512 threads
constexpr int STG       = 4096;               // fp32 path: 4 bufs x 1KB per wave
constexpr int QSTRIDE   = 5120;               // fp16 path: 1KB W + 4KB x per quad
constexpr int CHQ       = 4;                  // fp16 path chunks -> 512 blocks

// ---------- fp16 path layout (float units) ----------
struct L16 {
    static constexpr size_t XSH_OFF = 0;                             // x fp16: [n][b] 16B
    static constexpr size_t XSH_SZ  = (size_t)NCAP * NB * 4;         // 294,912
    static constexpr size_t WH_OFF  = XSH_OFF + XSH_SZ;              // W fp16: 256B/row
    static constexpr size_t WH_SZ   = (size_t)NCLS * NCAP * 64;      // 9,437,184
    static constexpr size_t P1_OFF  = WH_OFF + WH_SZ;
    static constexpr size_t P1_SZ   = (size_t)NCLS * CHQ * DOUT * NB;
    static constexpr size_t P2_OFF  = P1_OFF + P1_SZ;
    static constexpr size_t P23_SZ  = (size_t)NCLS * CHQ * (DOUT + 1) * NB;
    static constexpr size_t P3_OFF  = P2_OFF + P23_SZ;
    static constexpr size_t VA_OFF  = P3_OFF + P23_SZ;
    static constexpr size_t V_SZ    = (size_t)NCLS * DOUT * NB;
    static constexpr size_t VB_OFF  = VA_OFF + V_SZ;
    static constexpr size_t TOTAL   = VB_OFF + V_SZ;
};

// ---------- fp32 fallback layout (R9) ----------
template<int CH> struct Layout {
    static constexpr size_t XS_OFF = 0;
    static constexpr size_t XS_SZ  = (size_t)NCAP * NB * DIN;
    static constexpr size_t P1_OFF = XS_OFF + XS_SZ;
    static constexpr size_t P1_SZ  = (size_t)NCLS * CH * DOUT * NB;
    static constexpr size_t P2_OFF = P1_OFF + P1_SZ;
    static constexpr size_t P23_SZ = (size_t)NCLS * CH * (DOUT + 1) * NB;
    static constexpr size_t P3_OFF = P2_OFF + P23_SZ;
    static constexpr size_t VA_OFF = P3_OFF + P23_SZ;
    static constexpr size_t V_SZ   = (size_t)NCLS * DOUT * NB;
    static constexpr size_t VB_OFF = VA_OFF + V_SZ;
    static constexpr size_t TOTAL  = VB_OFF + V_SZ;
};

#define WAITV(N) asm volatile("s_waitcnt vmcnt(" #N ")" ::: "memory")
#define SB() __builtin_amdgcn_sched_barrier(0)
#define AS1 __attribute__((address_space(1)))
#define AS3 __attribute__((address_space(3)))

__device__ __forceinline__ float fdot2(half2_t a, half2_t b, float c) {
#if __has_builtin(__builtin_amdgcn_fdot2)
    return __builtin_amdgcn_fdot2(a, b, c, false);
#else
    asm volatile("v_dot2_f32_f16 %0, %1, %2, %0" : "+v"(c) : "v"(a), "v"(b));
    return c;
#endif
}
__device__ __forceinline__ half2_t bch2(float f) { return __builtin_bit_cast(half2_t, f); }
__device__ __forceinline__ float bcf(half2_t h) { return __builtin_bit_cast(float, h); }

// DPP quad-perm adds: VALU cross-lane within each 4-lane quad (no LDS port).
__device__ __forceinline__ float dpp_add_xor1(float v) {   // lane ^= 1
    int s = __builtin_amdgcn_update_dpp(0, __builtin_bit_cast(int, v),
                                        0xB1, 0xF, 0xF, true);
    return v + __builtin_bit_cast(float, s);
}
__device__ __forceinline__ float dpp_add_xor2(float v) {   // lane ^= 2
    int s = __builtin_amdgcn_update_dpp(0, __builtin_bit_cast(int, v),
                                        0x4E, 0xF, 0xF, true);
    return v + __builtin_bit_cast(float, s);
}

// ---- prep_x: squash(x), convert fp16, transpose to xsh[n][b] (4 half2 = 16B)
__global__ __launch_bounds__(256) void prep_x(const float* __restrict__ x,
                                              float* __restrict__ xsh) {
    const int g = blockIdx.x * 256 + threadIdx.x;   // g = n*64 + b
    const int n = g >> 6;
    const int b = g & 63;
    const float4* xp = reinterpret_cast<const float4*>(x + ((size_t)b * NCAP + n) * DIN);
    float4 a = xp[0], c4 = xp[1];
    float sq = a.x*a.x + a.y*a.y + a.z*a.z + a.w*a.w
             + c4.x*c4.x + c4.y*c4.y + c4.z*c4.z + c4.w*c4.w;
    float sc = sq / ((1.0f + sq) * sqrtf(sq));
    half2_t h0 = {(half_t)(a.x*sc),  (half_t)(a.y*sc)};
    half2_t h1 = {(half_t)(a.z*sc),  (half_t)(a.w*sc)};
    half2_t h2 = {(half_t)(c4.x*sc), (half_t)(c4.y*sc)};
    half2_t h3 = {(half_t)(c4.z*sc), (half_t)(c4.w*sc)};
    float4 o;
    o.x = bcf(h0); o.y = bcf(h1); o.z = bcf(h2); o.w = bcf(h3);
    reinterpret_cast<float4*>(xsh)[g] = o;
}

// ---- prep_w: W row (c,n) -> fp16 half2 pairs, layout [ip][o], 256B/row.
__global__ __launch_bounds__(256) void prep_w(const float* __restrict__ W,
                                              float* __restrict__ wh) {
    const int g   = blockIdx.x * 256 + threadIdx.x;
    const int row = g >> 2;
    const int ip  = g & 3;
    const float4* src = reinterpret_cast<const float4*>(W + (size_t)row * 128 + ip * 32);
    float4 a0 = src[0], a1 = src[1], a2 = src[2], a3 = src[3];   // W[2ip][0..15]
    float4 b0 = src[4], b1 = src[5], b2 = src[6], b3 = src[7];   // W[2ip+1][0..15]
    const float f0[16] = {a0.x,a0.y,a0.z,a0.w, a1.x,a1.y,a1.z,a1.w,
                          a2.x,a2.y,a2.z,a2.w, a3.x,a3.y,a3.z,a3.w};
    const float f1[16] = {b0.x,b0.y,b0.z,b0.w, b1.x,b1.y,b1.z,b1.w,
                          b2.x,b2.y,b2.z,b2.w, b3.x,b3.y,b3.z,b3.w};
    float4 d[4];
#pragma unroll
    for (int j = 0; j < 4; ++j) {
        half2_t h0 = {(half_t)f0[4*j+0], (half_t)f1[4*j+0]};
        half2_t h1 = {(half_t)f0[4*j+1], (half_t)f1[4*j+1]};
        half2_t h2 = {(half_t)f0[4*j+2], (half_t)f1[4*j+2]};
        half2_t h3 = {(half_t)f0[4*j+3], (half_t)f1[4*j+3]};
        d[j].x = bcf(h0); d[j].y = bcf(h1); d[j].z = bcf(h2); d[j].w = bcf(h3);
    }
    float4* dst = reinterpret_cast<float4*>(wh + (size_t)row * 64 + ip * 16);
    dst[0] = d[0]; dst[1] = d[1]; dst[2] = d[2]; dst[3] = d[3];
}

// ---- fp16 sweep, (4b,4o) lane split. Quad = 4 rows; staged as 1KB W + 4KB x.
template<bool WEIGHTED, int CH>
__global__ __launch_bounds__(SWEEP_BLK, 4) void sweep_q(const float* __restrict__ xsh,
                                                        const float* __restrict__ wh,
                                                        float* __restrict__ P,
                                                        const float* __restrict__ vbuf) {
    constexpr int NPC = NCAP / CH;      // 288 rows per block
    constexpr int NPW = NPC / NW;       // 36 rows per wave
    constexpr int NPQ = NPW / 4;        // 9 quads per wave
    static_assert(NPW * NW == NPC && NPQ * 4 == NPW, "geometry");

    const int bg_ = blockIdx.x;          // = c*CH + ch
    const int c   = bg_ / CH;
    const int ch  = bg_ % CH;
    const int lane = threadIdx.x & 63;
    const int w    = threadIdx.x >> 6;
    const int oq   = lane & 3;           // o-quarter: o = oq*4..oq*4+3
    const int bg   = lane >> 2;          // batch group: b = bg*4..bg*4+3

    // per-wave: 2-quad ring x (1KB W + 4KB x) = 10KB; total 80KB (union w/ red)
    __shared__ __align__(16) char smem[NW * 2 * QSTRIDE];

    // V (weighted): Vf[j][k] = V[c][oq*4+k][bg*4+j]
    float Vf[4][4];
    if (WEIGHTED) {
        const float* vb = vbuf + (size_t)c * DOUT * NB;
#pragma unroll
        for (int j = 0; j < 4; ++j)
#pragma unroll
            for (int k = 0; k < 4; ++k)
                Vf[j][k] = vb[(oq * 4 + k) * NB + bg * 4 + j];
    }
    WAITV(0);   // drain V loads so the vm FIFO is clean for counted staging

    float S[4][4];
#pragma unroll
    for (int j = 0; j < 4; ++j)
#pragma unroll
        for (int k = 0; k < 4; ++k) S[j][k] = 0.f;
    float Zr[4] = {0.f, 0.f, 0.f, 0.f};

    const int n0 = ch * NPC + w * NPW;
    const char* wsrc = (const char*)wh + ((size_t)c * NCAP + n0) * 256;
    const char* xsrc = (const char*)xsh + (size_t)n0 * 1024;
    char* mybuf = smem + w * (2 * QSTRIDE);

    // x staging source swizzle (involution): slot L holds batch L^(L>>3).
    const int xl = lane ^ (lane >> 3);
    int xpos[4];
#pragma unroll
    for (int j = 0; j < 4; ++j) {
        const int b = bg * 4 + j;
        xpos[j] = b ^ (b >> 3);
    }

    auto STAGEQ = [&](int q) {   // 5 vm ops: W(1KB) + 4 x rows (1KB each)
        char* dst = mybuf + (q & 1) * QSTRIDE;
        __builtin_amdgcn_global_load_lds(
            (const AS1 void*)(wsrc + (size_t)q * 1024 + lane * 16),
            (AS3 void*)(dst), 16, 0, 0);
#pragma unroll
        for (int r = 0; r < 4; ++r) {
            __builtin_amdgcn_global_load_lds(
                (const AS1 void*)(xsrc + (size_t)(4 * q + r) * 1024 + xl * 16),
                (AS3 void*)(dst + 1024 + r * 1024), 16, 0, 0);
        }
    };

    auto ROWF = [&](int q, int r) {
        const char* buf  = mybuf + (q & 1) * QSTRIDE;
        const char* wrow = buf + r * 256 + oq * 16;
        f4v wip[4];
#pragma unroll
        for (int ip = 0; ip < 4; ++ip)
            wip[ip] = *reinterpret_cast<const f4v*>(wrow + ip * 64);
        const char* xq = buf + 1024 + r * 1024;
        f4v xb[4];
#pragma unroll
        for (int j = 0; j < 4; ++j)
            xb[j] = *reinterpret_cast<const f4v*>(xq + xpos[j] * 16);

        if (!WEIGHTED) {
#pragma unroll
            for (int ip = 0; ip < 4; ++ip)
#pragma unroll
                for (int j = 0; j < 4; ++j) {
                    const half2_t xj = bch2(xb[j][ip]);
#pragma unroll
                    for (int k = 0; k < 4; ++k)
                        S[j][k] = fdot2(xj, bch2(wip[ip][k]), S[j][k]);
                }
        } else {
            float u[4][4];
#pragma unroll
            for (int j = 0; j < 4; ++j)
#pragma unroll
                for (int k = 0; k < 4; ++k) u[j][k] = 0.f;
#pragma unroll
            for (int ip = 0; ip < 4; ++ip)
#pragma unroll
                for (int j = 0; j < 4; ++j) {
                    const half2_t xj = bch2(xb[j][ip]);
#pragma unroll
                    for (int k = 0; k < 4; ++k)
                        u[j][k] = fdot2(xj, bch2(wip[ip][k]), u[j][k]);
                }
            float bdp[4];
#pragma unroll
            for (int j = 0; j < 4; ++j) {
                float t = u[j][0] * Vf[j][0];
                t = fmaf(u[j][1], Vf[j][1], t);
                t = fmaf(u[j][2], Vf[j][2], t);
                t = fmaf(u[j][3], Vf[j][3], t);
                bdp[j] = t;
            }
            // 4-lane o-group sum via DPP quad-perm (VALU, no LDS port)
#pragma unroll
            for (int j = 0; j < 4; ++j) bdp[j] = dpp_add_xor1(bdp[j]);
#pragma unroll
            for (int j = 0; j < 4; ++j) bdp[j] = dpp_add_xor2(bdp[j]);
#pragma unroll
            for (int j = 0; j < 4; ++j) {
                const float g = __expf(bdp[j]);   // |bd| <= ~48, fp32-safe
                Zr[j] += g;
#pragma unroll
                for (int k = 0; k < 4; ++k)
                    S[j][k] = fmaf(g, u[j][k], S[j][k]);
            }
        }
    };

    // ---- pipeline: quad q+1 staged while computing quad q. vmcnt(5) steady.
    STAGEQ(0);
#pragma unroll 1
    for (int q = 0; q < NPQ; ++q) {
        if (q + 1 < NPQ) { STAGEQ(q + 1); SB(); WAITV(5); SB(); }
        else             { SB(); WAITV(0); SB(); }
        ROWF(q, 0); ROWF(q, 1); ROWF(q, 2); ROWF(q, 3);
    }

    // ---- cross-wave merge (reuse smem after staging consumed)
    __syncthreads();
    float (*red)[DOUT + 1][NB] = reinterpret_cast<float (*)[DOUT + 1][NB]>(smem);
#pragma unroll
    for (int j = 0; j < 4; ++j)
#pragma unroll
        for (int k = 0; k < 4; ++k)
            red[w][oq * 4 + k][bg * 4 + j] = S[j][k];
    if (WEIGHTED) {
        if (oq == 0) {
#pragma unroll
            for (int j = 0; j < 4; ++j) red[w][DOUT][bg * 4 + j] = Zr[j];
        }
    }
    __syncthreads();
    for (int idx = threadIdx.x; idx < (DOUT + 1) * NB; idx += SWEEP_BLK) {
        const int slot = idx >> 6;
        const int bb   = idx & 63;
        float acc = 0.f;
#pragma unroll
        for (int k = 0; k < NW; ++k) acc += red[k][slot][bb];
        if (!WEIGHTED) {
            if (slot < DOUT)
                P[((size_t)bg_ * DOUT + slot) * NB + bb] = acc;
        } else {
            P[((size_t)bg_ * (DOUT + 1) + slot) * NB + bb] = acc;
        }
    }
}

// ================= fp32 fallback path (R9, proven) =================
__global__ __launch_bounds__(256) void prep_kernel(const float* __restrict__ x,
                                                   float* __restrict__ xs) {
    const int g = blockIdx.x * 256 + threadIdx.x;
    const int n = g >> 6;
    const int b = g & 63;
    const float4* xp = reinterpret_cast<const float4*>(x + ((size_t)b * NCAP + n) * DIN);
    float4 a = xp[0], c4 = xp[1];
    float sq = a.x*a.x + a.y*a.y + a.z*a.z + a.w*a.w
             + c4.x*c4.x + c4.y*c4.y + c4.z*c4.z + c4.w*c4.w;
    float sc = sq / ((1.0f + sq) * sqrtf(sq));
    float4 o0 = {a.x*sc,  a.y*sc,  a.z*sc,  a.w*sc};
    float4 o1 = {c4.x*sc, c4.y*sc, c4.z*sc, c4.w*sc};
    float4* op = reinterpret_cast<float4*>(xs + (size_t)g * DIN);
    op[0] = o0;
    op[1] = o1;
}

template<bool WEIGHTED, int CH>
__global__ __launch_bounds__(SWEEP_BLK, 2) void sweep_kernel(const float* __restrict__ xs,
                                                             const float* __restrict__ W,
                                                             float* __restrict__ P,
                                                             const float* __restrict__ vbuf) {
    constexpr int NPC    = NCAP / CH;
    constexpr int NPW    = NPC / NW;
    constexpr int NPAIRS = NPW / 2;

    const int bg = blockIdx.x;
    const int c  = bg / CH;
    const int ch = bg % CH;
    const int b  = threadIdx.x & 63;
    const int w  = threadIdx.x >> 6;

    __shared__ __align__(16) char smem[NW * (DOUT + 1) * NB * 4];

    float V[DOUT];
    if (WEIGHTED) {
        const float* vb = vbuf + (size_t)c * DOUT * NB + b;
#pragma unroll
        for (int o = 0; o < DOUT; ++o) V[o] = vb[o * NB];
    }

    float S[DOUT];
#pragma unroll
    for (int o = 0; o < DOUT; ++o) S[o] = 0.f;
    float Z = 0.f;

    const int n0 = ch * NPC + w * NPW;
    const char* wsrc = (const char*)W + ((size_t)c * NCAP + n0) * 512;
    char* mybuf = smem + w * STG;

    auto STAGE = [&](int p) {
        __builtin_amdgcn_global_load_lds(
            (const AS1 void*)(wsrc + (size_t)p * 1024 + b * 16),
            (AS3 void*)(mybuf + (p & 3) * 1024), 16, 0, 0);
    };
    auto XROW = [&](int row, float4& xa, float4& xb) {
        const float4* xp = reinterpret_cast<const float4*>(
            xs + ((size_t)(n0 + row) * NB + b) * DIN);
        xa = xp[0];
        xb = xp[1];
    };
    auto ROW = [&](int p, int r, float4 xa, float4 xb) {
        const float4* wl = reinterpret_cast<const float4*>(mybuf + (p & 3) * 1024 + r * 512);
        const float xv[DIN] = {xa.x, xa.y, xa.z, xa.w, xb.x, xb.y, xb.z, xb.w};
        if (!WEIGHTED) {
#pragma unroll
            for (int i = 0; i < DIN; ++i) {
                float4 q0 = wl[i*4+0], q1 = wl[i*4+1], q2 = wl[i*4+2], q3 = wl[i*4+3];
                const float xi = xv[i];
                S[ 0]=fmaf(xi,q0.x,S[ 0]); S[ 1]=fmaf(xi,q0.y,S[ 1]);
                S[ 2]=fmaf(xi,q0.z,S[ 2]); S[ 3]=fmaf(xi,q0.w,S[ 3]);
                S[ 4]=fmaf(xi,q1.x,S[ 4]); S[ 5]=fmaf(xi,q1.y,S[ 5]);
                S[ 6]=fmaf(xi,q1.z,S[ 6]); S[ 7]=fmaf(xi,q1.w,S[ 7]);
                S[ 8]=fmaf(xi,q2.x,S[ 8]); S[ 9]=fmaf(xi,q2.y,S[ 9]);
                S[10]=fmaf(xi,q2.z,S[10]); S[11]=fmaf(xi,q2.w,S[11]);
                S[12]=fmaf(xi,q3.x,S[12]); S[13]=fmaf(xi,q3.y,S[13]);
                S[14]=fmaf(xi,q3.z,S[14]); S[15]=fmaf(xi,q3.w,S[15]);
            }
        } else {
            float u[DOUT];
#pragma unroll
            for (int o = 0; o < DOUT; ++o) u[o] = 0.f;
#pragma unroll
            for (int i = 0; i < DIN; ++i) {
                float4 q0 = wl[i*4+0], q1 = wl[i*4+1], q2 = wl[i*4+2], q3 = wl[i*4+3];
                const float xi = xv[i];
                u[ 0]=fmaf(xi,q0.x,u[ 0]); u[ 1]=fmaf(xi,q0.y,u[ 1]);
                u[ 2]=fmaf(xi,q0.z,u[ 2]); u[ 3]=fmaf(xi,q0.w,u[ 3]);
                u[ 4]=fmaf(xi,q1.x,u[ 4]); u[ 5]=fmaf(xi,q1.y,u[ 5]);
                u[ 6]=fmaf(xi,q1.z,u[ 6]); u[ 7]=fmaf(xi,q1.w,u[ 7]);
                u[ 8]=fmaf(xi,q2.x,u[ 8]); u[ 9]=fmaf(xi,q2.y,u[ 9]);
                u[10]=fmaf(xi,q2.z,u[10]); u[11]=fmaf(xi,q2.w,u[11]);
                u[12]=fmaf(xi,q3.x,u[12]); u[13]=fmaf(xi,q3.y,u[13]);
                u[14]=fmaf(xi,q3.z,u[14]); u[15]=fmaf(xi,q3.w,u[15]);
            }
            float bd = 0.f;
#pragma unroll
            for (int o = 0; o < DOUT; ++o) bd = fmaf(u[o], V[o], bd);
            const float g = __expf(bd);
            Z += g;
#pragma unroll
            for (int o = 0; o < DOUT; ++o) S[o] = fmaf(g, u[o], S[o]);
        }
    };

    STAGE(0); SB();
    STAGE(1); SB();
    float4 ca0, ca1, cb0, cb1, na0, na1, nb0, nb1;
    XROW(0, ca0, ca1);
    XROW(1, cb0, cb1);
    SB();

#pragma unroll 1
    for (int p = 0; p < NPAIRS; ++p) {
        if (p + 2 < NPAIRS) STAGE(p + 2);
        SB();
        if (p + 1 < NPAIRS) {
            XROW(2 * (p + 1),     na0, na1);
            XROW(2 * (p + 1) + 1, nb0, nb1);
        }
        SB();
        if (p < NPAIRS - 2)       { WAITV(5); }
        else if (p == NPAIRS - 2) { WAITV(4); }
        else                      { WAITV(0); }
        SB();
        ROW(p, 0, ca0, ca1);
        ROW(p, 1, cb0, cb1);
        ca0 = na0; ca1 = na1; cb0 = nb0; cb1 = nb1;
    }

    __syncthreads();
    float (*red)[DOUT + 1][NB] = reinterpret_cast<float (*)[DOUT + 1][NB]>(smem);
#pragma unroll
    for (int o = 0; o < DOUT; ++o) red[w][o][b] = S[o];
    red[w][DOUT][b] = Z;
    __syncthreads();
    for (int idx = threadIdx.x; idx < (DOUT + 1) * NB; idx += SWEEP_BLK) {
        const int slot = idx >> 6;
        const int bb   = idx & 63;
        float acc = 0.f;
#pragma unroll
        for (int k = 0; k < NW; ++k) acc += red[k][slot][bb];
        if (!WEIGHTED) {
            if (slot < DOUT)
                P[((size_t)bg * DOUT + slot) * NB + bb] = acc;
        } else {
            P[((size_t)bg * (DOUT + 1) + slot) * NB + bb] = acc;
        }
    }
}

// ---- vupd: merge partials -> V. MODE1: squash(sum/N). MODE2: vin + squash(S/Z).
template<int MODE, int CH>
__global__ __launch_bounds__(64) void vupd_kernel(const float* __restrict__ P,
                                                  const float* __restrict__ vin,
                                                  float* __restrict__ vout) {
    const int c = blockIdx.x;
    const int b = threadIdx.x;

    float s[DOUT];
    float sq = 0.f;
    if (MODE == 1) {
#pragma unroll
        for (int o = 0; o < DOUT; ++o) {
            float acc = 0.f;
#pragma unroll
            for (int k = 0; k < CH; ++k)
                acc += P[(((size_t)c * CH + k) * DOUT + o) * NB + b];
            acc *= (1.0f / (float)NCAP);
            s[o] = acc;
            sq += acc * acc;
        }
    } else {
        float Zt = 0.f;
#pragma unroll
        for (int k = 0; k < CH; ++k)
            Zt += P[(((size_t)c * CH + k) * (DOUT + 1) + DOUT) * NB + b];
        const float rz = 1.0f / Zt;
#pragma unroll
        for (int o = 0; o < DOUT; ++o) {
            float acc = 0.f;
#pragma unroll
            for (int k = 0; k < CH; ++k)
                acc += P[(((size_t)c * CH + k) * (DOUT + 1) + o) * NB + b];
            acc *= rz;
            s[o] = acc;
            sq += acc * acc;
        }
    }
    const float sc = sq / ((1.0f + sq) * sqrtf(sq));
#pragma unroll
    for (int o = 0; o < DOUT; ++o) {
        float v = s[o] * sc;
        if (MODE == 2) v += vin[((size_t)c * DOUT + o) * NB + b];
        vout[((size_t)c * DOUT + o) * NB + b] = v;
    }
}

// ---- final: merge P3 -> v3, leaky^2, per-batch normalize
template<int CH>
__global__ __launch_bounds__(256) void final_kernel(const float* __restrict__ P3,
                                                    float* __restrict__ out) {
    const int b    = blockIdx.x;
    const int tid  = threadIdx.x;
    const int c    = tid >> 1;
    const int half = tid & 1;

    float Zt = 0.f;
#pragma unroll
    for (int k = 0; k < CH; ++k)
        Zt += P3[(((size_t)c * CH + k) * (DOUT + 1) + DOUT) * NB + b];
    const float rz = 1.0f / Zt;

    float s[8];
    float sqh = 0.f;
#pragma unroll
    for (int j = 0; j < 8; ++j) {
        const int o = half * 8 + j;
        float acc = 0.f;
#pragma unroll
        for (int k = 0; k < CH; ++k)
            acc += P3[(((size_t)c * CH + k) * (DOUT + 1) + o) * NB + b];
        acc *= rz;
        s[j] = acc;
        sqh += acc * acc;
    }
    const float sq = sqh + __shfl_xor(sqh, 1);
    const float sc = sq / ((1.0f + sq) * sqrtf(sq));

    float val[8];
    float ps = 0.f;
#pragma unroll
    for (int j = 0; j < 8; ++j) {
        const float v = s[j] * sc;
        const float l = v > 0.f ? v : 0.01f * v;
        val[j] = l * l;
        ps += val[j];
    }
#pragma unroll
    for (int off = 1; off < 64; off <<= 1) ps += __shfl_xor(ps, off);
    __shared__ float wsum[4];
    if ((tid & 63) == 0) wsum[tid >> 6] = ps;
    __syncthreads();
    const float inv = 1.0f / (wsum[0] + wsum[1] + wsum[2] + wsum[3]);
#pragma unroll
    for (int j = 0; j < 8; ++j)
        out[((size_t)b * NCLS + c) * DOUT + half * 8 + j] = val[j] * inv;
}

template<int CH>
static void run_f32(const float* x, const float* W, float* out, float* ws,
                    hipStream_t stream) {
    using L = Layout<CH>;
    float* xs = ws + L::XS_OFF;
    float* P1 = ws + L::P1_OFF;
    float* P2 = ws + L::P2_OFF;
    float* P3 = ws + L::P3_OFF;
    float* VA = ws + L::VA_OFF;
    float* VB = ws + L::VB_OFF;

    hipLaunchKernelGGL(prep_kernel, dim3(NCAP * NB / 256), dim3(256), 0, stream, x, xs);
    hipLaunchKernelGGL((sweep_kernel<false, CH>), dim3(NCLS * CH), dim3(SWEEP_BLK), 0,
                       stream, xs, W, P1, nullptr);
    hipLaunchKernelGGL((vupd_kernel<1, CH>), dim3(NCLS), dim3(64), 0, stream,
                       P1, nullptr, VA);
    hipLaunchKernelGGL((sweep_kernel<true, CH>), dim3(NCLS * CH), dim3(SWEEP_BLK), 0,
                       stream, xs, W, P2, VA);
    hipLaunchKernelGGL((vupd_kernel<2, CH>), dim3(NCLS), dim3(64), 0, stream,
                       P2, VA, VB);
    hipLaunchKernelGGL((sweep_kernel<true, CH>), dim3(NCLS * CH), dim3(SWEEP_BLK), 0,
                       stream, xs, W, P3, VB);
    hipLaunchKernelGGL((final_kernel<CH>), dim3(NB), dim3(256), 0, stream, P3, out);
}

extern "C" void kernel_launch(void* const* d_in, const int* in_sizes, int n_in,
                              void* d_out, int out_size, void* d_ws, size_t ws_size,
                              hipStream_t stream) {
    const float* x = (const float*)d_in[0];
    const float* W = (const float*)d_in[1];
    float* out = (float*)d_out;
    float* ws  = (float*)d_ws;

    if (ws_size >= L16::TOTAL * sizeof(float)) {
        float* xsh = ws + L16::XSH_OFF;
        float* wh  = ws + L16::WH_OFF;
        float* P1  = ws + L16::P1_OFF;
        float* P2  = ws + L16::P2_OFF;
        float* P3  = ws + L16::P3_OFF;
        float* VA  = ws + L16::VA_OFF;
        float* VB  = ws + L16::VB_OFF;

        hipLaunchKernelGGL(prep_x, dim3(NCAP * NB / 256), dim3(256), 0, stream, x, xsh);
        hipLaunchKernelGGL(prep_w, dim3(NCLS * NCAP * 4 / 256), dim3(256), 0, stream, W, wh);
        hipLaunchKernelGGL((sweep_q<false, CHQ>), dim3(NCLS * CHQ), dim3(SWEEP_BLK), 0,
                           stream, xsh, wh, P1, nullptr);
        hipLaunchKernelGGL((vupd_kernel<1, CHQ>), dim3(NCLS), dim3(64), 0, stream,
                           P1, nullptr, VA);
        hipLaunchKernelGGL((sweep_q<true, CHQ>), dim3(NCLS * CHQ), dim3(SWEEP_BLK), 0,
                           stream, xsh, wh, P2, VA);
        hipLaunchKernelGGL((vupd_kernel<2, CHQ>), dim3(NCLS), dim3(64), 0, stream,
                           P2, VA, VB);
        hipLaunchKernelGGL((sweep_q<true, CHQ>), dim3(NCLS * CHQ), dim3(SWEEP_BLK), 0,
                           stream, xsh, wh, P3, VB);
        hipLaunchKernelGGL((final_kernel<CHQ>), dim3(NB), dim3(256), 0, stream, P3, out);
    } else if (ws_size >= Layout<8>::TOTAL * sizeof(float)) {
        run_f32<8>(x, W, out, ws, stream);
    } else {
        run_f32<4>(x, W, out, ws, stream);
    }
}

// Round 16
// 130.082 us; speedup vs baseline: 1.1998x; 1.1544x over previous
//
#include <hip/hip_runtime.h>
#include <math.h>

// CapsNet dynamic routing — MFMA reformulation (mfma_f32_16x16x32_f16).
//
// R13/R15 analysis: VALU/LDS-port both saturated ~100x above the math floor
// because u = x@W is matmul-shaped work on the vector ALU. R16: u via MFMA.
//   A-frag = w2t[c][o][k=n*8+i] (M=o=16), B-frag = xsh[n][b] (N=b=16) —
//   existing xsh layout IS the B fragment. Unweighted sweep: dense C += A@B
//   (sums over n automatically). Weighted: 4 block-diag MFMAs per K-step
//   (B tile n' = grp==n' ? x : 0) -> per-n u^T tiles (C: row=o, col=b, m89);
//   bd = 4 fma + xor16/xor32 shfl butterfly; direct global P writes, zero LDS.
//
// x: [B=64, N=1152, Din=8], W: [C=128, N=1152, Din=8, Dout=16]
// out: [B=64, C=128, Dout=16]

typedef _Float16 half_t;
typedef _Float16 half8 __attribute__((ext_vector_type(8)));
typedef float f32x4 __attribute__((ext_vector_type(4)));

constexpr int NCAP = 1152;
constexpr int DIN  = 8;
constexpr int DOUT = 16;
constexpr int NCLS = 128;
constexpr int NB   = 64;

constexpr int CHM = 8;   // K-chunks per class -> 1024 blocks

// ---------- MFMA path layout (float units) ----------
struct LM {
    static constexpr size_t XSH_OFF = 0;                              // x fp16 [n][b] 16B
    static constexpr size_t XSH_SZ  = (size_t)NCAP * NB * 4;          // 294,912
    static constexpr size_t W2T_OFF = XSH_OFF + XSH_SZ;               // W fp16 [c][o][k]
    static constexpr size_t W2T_SZ  = (size_t)NCLS * DOUT * NCAP * DIN / 2;  // 9,437,184
    static constexpr size_t P1_OFF  = W2T_OFF + W2T_SZ;
    static constexpr size_t P1_SZ   = (size_t)NCLS * CHM * DOUT * NB;
    static constexpr size_t P2_OFF  = P1_OFF + P1_SZ;
    static constexpr size_t P23_SZ  = (size_t)NCLS * CHM * (DOUT + 1) * NB;
    static constexpr size_t P3_OFF  = P2_OFF + P23_SZ;
    static constexpr size_t VA_OFF  = P3_OFF + P23_SZ;
    static constexpr size_t V_SZ    = (size_t)NCLS * DOUT * NB;
    static constexpr size_t VB_OFF  = VA_OFF + V_SZ;
    static constexpr size_t TOTAL   = VB_OFF + V_SZ;                  // ~13.3M floats
};

// ---------- fp32 fallback layout (R9, proven) ----------
template<int CH> struct Layout {
    static constexpr size_t XS_OFF = 0;
    static constexpr size_t XS_SZ  = (size_t)NCAP * NB * DIN;
    static constexpr size_t P1_OFF = XS_OFF + XS_SZ;
    static constexpr size_t P1_SZ  = (size_t)NCLS * CH * DOUT * NB;
    static constexpr size_t P2_OFF = P1_OFF + P1_SZ;
    static constexpr size_t P23_SZ = (size_t)NCLS * CH * (DOUT + 1) * NB;
    static constexpr size_t P3_OFF = P2_OFF + P23_SZ;
    static constexpr size_t VA_OFF = P3_OFF + P23_SZ;
    static constexpr size_t V_SZ   = (size_t)NCLS * DOUT * NB;
    static constexpr size_t VB_OFF = VA_OFF + V_SZ;
    static constexpr size_t TOTAL  = VB_OFF + V_SZ;
};

#define WAITV(N) asm volatile("s_waitcnt vmcnt(" #N ")" ::: "memory")
#define SB() __builtin_amdgcn_sched_barrier(0)
#define AS1 __attribute__((address_space(1)))
#define AS3 __attribute__((address_space(3)))

__device__ __forceinline__ half8 bch8(const void* p) {
    return *reinterpret_cast<const half8*>(p);
}

// ---- prep_x: squash(x), convert fp16, transpose to xsh[n][b] (8 halfs = 16B)
__global__ __launch_bounds__(256) void prep_x(const float* __restrict__ x,
                                              float* __restrict__ xsh) {
    const int g = blockIdx.x * 256 + threadIdx.x;   // g = n*64 + b
    const int n = g >> 6;
    const int b = g & 63;
    const float4* xp = reinterpret_cast<const float4*>(x + ((size_t)b * NCAP + n) * DIN);
    float4 a = xp[0], c4 = xp[1];
    float sq = a.x*a.x + a.y*a.y + a.z*a.z + a.w*a.w
             + c4.x*c4.x + c4.y*c4.y + c4.z*c4.z + c4.w*c4.w;
    float sc = sq / ((1.0f + sq) * sqrtf(sq));
    half8 h = {(half_t)(a.x*sc),  (half_t)(a.y*sc),  (half_t)(a.z*sc),  (half_t)(a.w*sc),
               (half_t)(c4.x*sc), (half_t)(c4.y*sc), (half_t)(c4.z*sc), (half_t)(c4.w*sc)};
    reinterpret_cast<half8*>(xsh)[g] = h;
}

// ---- prep_w2: W[c,n,i,o] fp32 -> w2t[c][o][k=n*8+i] fp16 (A-fragment layout).
// thread = (c, n, o): reads W[c,n,0..7,o] (8 strided floats), writes 16B.
__global__ __launch_bounds__(256) void prep_w2(const float* __restrict__ W,
                                               float* __restrict__ w2t) {
    const int t   = blockIdx.x * 256 + threadIdx.x;   // < 128*1152*16
    const int c   = t / (NCAP * DOUT);
    const int rem = t % (NCAP * DOUT);
    const int n   = rem >> 4;
    const int o   = rem & 15;
    const float* src = W + ((size_t)(c * NCAP + n) * DIN) * DOUT + o;
    half8 h;
#pragma unroll
    for (int i = 0; i < DIN; ++i) h[i] = (half_t)src[i * DOUT];
    half_t* dst = reinterpret_cast<half_t*>(w2t) +
                  ((size_t)(c * DOUT + o) * NCAP + n) * DIN;
    *reinterpret_cast<half8*>(dst) = h;
}

// ---- sweep_m: MFMA sweep. Block = 256 thr = 4 waves (one b-tile each).
// K-step = 4 n's (K=32). Unweighted: dense accumulate. Weighted: 4 block-diag
// MFMAs -> per-n u^T (row=o, col=b), bd butterfly, exp, S/Z accumulate.
template<bool WEIGHTED, int CH>
__global__ __launch_bounds__(256, 4) void sweep_m(const float* __restrict__ xsh,
                                                  const float* __restrict__ w2t,
                                                  float* __restrict__ P,
                                                  const float* __restrict__ vbuf) {
    constexpr int NPC = NCAP / CH;   // 144 n per chunk
    constexpr int KS  = NPC / 4;     // 36 K-steps

    const int bgid = blockIdx.x;     // = c*CH + ch
    const int c    = bgid / CH;
    const int ch   = bgid % CH;
    const int lane = threadIdx.x & 63;
    const int w    = threadIdx.x >> 6;   // b-tile 0..3
    const int grp  = lane >> 4;          // 0..3 (K-group / o-row-group)
    const int li   = lane & 15;          // M(o) for A, N(b) for B/C
    const int bidx = w * 16 + li;        // this lane's batch column

    const half_t* wb = reinterpret_cast<const half_t*>(w2t) +
                       (size_t)(c * DOUT + li) * (NCAP * DIN);
    const half_t* xb = reinterpret_cast<const half_t*>(xsh);
    const int nb0 = ch * NPC;

    float Vf[4];
    if (WEIGHTED) {
#pragma unroll
        for (int r = 0; r < 4; ++r)
            Vf[r] = vbuf[((size_t)c * DOUT + grp * 4 + r) * NB + bidx];
    }

    auto LDA = [&](int ks) -> half8 {
        return bch8(wb + (size_t)(nb0 + ks * 4 + grp) * DIN);
    };
    auto LDX = [&](int ks) -> half8 {
        return bch8(xb + ((size_t)(nb0 + ks * 4 + grp) * NB + bidx) * DIN);
    };

    f32x4 S = {0.f, 0.f, 0.f, 0.f};
    float Z = 0.f;
    const half8 hz = {};
    const f32x4 fz = {0.f, 0.f, 0.f, 0.f};

    half8 a_c = LDA(0), x_c = LDX(0);
    half8 a_n = a_c, x_n = x_c;

#pragma unroll 1
    for (int ks = 0; ks < KS; ++ks) {
        if (ks + 1 < KS) { a_n = LDA(ks + 1); x_n = LDX(ks + 1); }
        if (!WEIGHTED) {
            S = __builtin_amdgcn_mfma_f32_16x16x32_f16(a_c, x_c, S, 0, 0, 0);
        } else {
            f32x4 u0 = __builtin_amdgcn_mfma_f32_16x16x32_f16(a_c, (grp == 0) ? x_c : hz, fz, 0, 0, 0);
            f32x4 u1 = __builtin_amdgcn_mfma_f32_16x16x32_f16(a_c, (grp == 1) ? x_c : hz, fz, 0, 0, 0);
            f32x4 u2 = __builtin_amdgcn_mfma_f32_16x16x32_f16(a_c, (grp == 2) ? x_c : hz, fz, 0, 0, 0);
            f32x4 u3 = __builtin_amdgcn_mfma_f32_16x16x32_f16(a_c, (grp == 3) ? x_c : hz, fz, 0, 0, 0);

            // bd partial over this grp's 4 o's
            float p0 = u0[0] * Vf[0], p1 = u1[0] * Vf[0],
                  p2 = u2[0] * Vf[0], p3 = u3[0] * Vf[0];
#pragma unroll
            for (int r = 1; r < 4; ++r) {
                p0 = fmaf(u0[r], Vf[r], p0);
                p1 = fmaf(u1[r], Vf[r], p1);
                p2 = fmaf(u2[r], Vf[r], p2);
                p3 = fmaf(u3[r], Vf[r], p3);
            }
            // butterfly over the 4 o-row-groups (lanes l, l^16, l^32, l^48)
            p0 += __shfl_xor(p0, 16); p1 += __shfl_xor(p1, 16);
            p2 += __shfl_xor(p2, 16); p3 += __shfl_xor(p3, 16);
            p0 += __shfl_xor(p0, 32); p1 += __shfl_xor(p1, 32);
            p2 += __shfl_xor(p2, 32); p3 += __shfl_xor(p3, 32);

            const float g0 = __expf(p0);   // |bd| <= ~48: fp32-safe
            const float g1 = __expf(p1);
            const float g2 = __expf(p2);
            const float g3 = __expf(p3);
#pragma unroll
            for (int r = 0; r < 4; ++r) {
                float s = S[r];
                s = fmaf(g0, u0[r], s);
                s = fmaf(g1, u1[r], s);
                s = fmaf(g2, u2[r], s);
                s = fmaf(g3, u3[r], s);
                S[r] = s;
            }
            Z += (g0 + g1) + (g2 + g3);
        }
        a_c = a_n; x_c = x_n;
    }

    // ---- direct global P writes (waves own disjoint b ranges; no LDS merge)
    if (!WEIGHTED) {
#pragma unroll
        for (int r = 0; r < 4; ++r)
            P[((size_t)bgid * DOUT + (grp * 4 + r)) * NB + bidx] = S[r];
    } else {
#pragma unroll
        for (int r = 0; r < 4; ++r)
            P[((size_t)bgid * (DOUT + 1) + (grp * 4 + r)) * NB + bidx] = S[r];
        if (grp == 0)
            P[((size_t)bgid * (DOUT + 1) + DOUT) * NB + bidx] = Z;
    }
}

// ---- vupd: merge partials -> V. MODE1: squash(sum/N). MODE2: vin + squash(S/Z).
template<int MODE, int CH>
__global__ __launch_bounds__(64) void vupd_kernel(const float* __restrict__ P,
                                                  const float* __restrict__ vin,
                                                  float* __restrict__ vout) {
    const int c = blockIdx.x;
    const int b = threadIdx.x;

    float s[DOUT];
    float sq = 0.f;
    if (MODE == 1) {
#pragma unroll
        for (int o = 0; o < DOUT; ++o) {
            float acc = 0.f;
#pragma unroll
            for (int k = 0; k < CH; ++k)
                acc += P[(((size_t)c * CH + k) * DOUT + o) * NB + b];
            acc *= (1.0f / (float)NCAP);
            s[o] = acc;
            sq += acc * acc;
        }
    } else {
        float Zt = 0.f;
#pragma unroll
        for (int k = 0; k < CH; ++k)
            Zt += P[(((size_t)c * CH + k) * (DOUT + 1) + DOUT) * NB + b];
        const float rz = 1.0f / Zt;
#pragma unroll
        for (int o = 0; o < DOUT; ++o) {
            float acc = 0.f;
#pragma unroll
            for (int k = 0; k < CH; ++k)
                acc += P[(((size_t)c * CH + k) * (DOUT + 1) + o) * NB + b];
            acc *= rz;
            s[o] = acc;
            sq += acc * acc;
        }
    }
    const float sc = sq / ((1.0f + sq) * sqrtf(sq));
#pragma unroll
    for (int o = 0; o < DOUT; ++o) {
        float v = s[o] * sc;
        if (MODE == 2) v += vin[((size_t)c * DOUT + o) * NB + b];
        vout[((size_t)c * DOUT + o) * NB + b] = v;
    }
}

// ---- final: merge P3 -> v3, leaky^2, per-batch normalize
template<int CH>
__global__ __launch_bounds__(256) void final_kernel(const float* __restrict__ P3,
                                                    float* __restrict__ out) {
    const int b    = blockIdx.x;
    const int tid  = threadIdx.x;
    const int c    = tid >> 1;
    const int half = tid & 1;

    float Zt = 0.f;
#pragma unroll
    for (int k = 0; k < CH; ++k)
        Zt += P3[(((size_t)c * CH + k) * (DOUT + 1) + DOUT) * NB + b];
    const float rz = 1.0f / Zt;

    float s[8];
    float sqh = 0.f;
#pragma unroll
    for (int j = 0; j < 8; ++j) {
        const int o = half * 8 + j;
        float acc = 0.f;
#pragma unroll
        for (int k = 0; k < CH; ++k)
            acc += P3[(((size_t)c * CH + k) * (DOUT + 1) + o) * NB + b];
        acc *= rz;
        s[j] = acc;
        sqh += acc * acc;
    }
    const float sq = sqh + __shfl_xor(sqh, 1);
    const float sc = sq / ((1.0f + sq) * sqrtf(sq));

    float val[8];
    float ps = 0.f;
#pragma unroll
    for (int j = 0; j < 8; ++j) {
        const float v = s[j] * sc;
        const float l = v > 0.f ? v : 0.01f * v;
        val[j] = l * l;
        ps += val[j];
    }
#pragma unroll
    for (int off = 1; off < 64; off <<= 1) ps += __shfl_xor(ps, off);
    __shared__ float wsum[4];
    if ((tid & 63) == 0) wsum[tid >> 6] = ps;
    __syncthreads();
    const float inv = 1.0f / (wsum[0] + wsum[1] + wsum[2] + wsum[3]);
#pragma unroll
    for (int j = 0; j < 8; ++j)
        out[((size_t)b * NCLS + c) * DOUT + half * 8 + j] = val[j] * inv;
}

// ================= fp32 fallback path (R9, proven) =================
constexpr int NW        = 8;
constexpr int SWEEP_BLK = NW * 64;
constexpr int STG       = 4096;

__global__ __launch_bounds__(256) void prep_kernel(const float* __restrict__ x,
                                                   float* __restrict__ xs) {
    const int g = blockIdx.x * 256 + threadIdx.x;
    const int n = g >> 6;
    const int b = g & 63;
    const float4* xp = reinterpret_cast<const float4*>(x + ((size_t)b * NCAP + n) * DIN);
    float4 a = xp[0], c4 = xp[1];
    float sq = a.x*a.x + a.y*a.y + a.z*a.z + a.w*a.w
             + c4.x*c4.x + c4.y*c4.y + c4.z*c4.z + c4.w*c4.w;
    float sc = sq / ((1.0f + sq) * sqrtf(sq));
    float4 o0 = {a.x*sc,  a.y*sc,  a.z*sc,  a.w*sc};
    float4 o1 = {c4.x*sc, c4.y*sc, c4.z*sc, c4.w*sc};
    float4* op = reinterpret_cast<float4*>(xs + (size_t)g * DIN);
    op[0] = o0;
    op[1] = o1;
}

template<bool WEIGHTED, int CH>
__global__ __launch_bounds__(SWEEP_BLK, 2) void sweep_kernel(const float* __restrict__ xs,
                                                             const float* __restrict__ W,
                                                             float* __restrict__ P,
                                                             const float* __restrict__ vbuf) {
    constexpr int NPC    = NCAP / CH;
    constexpr int NPW    = NPC / NW;
    constexpr int NPAIRS = NPW / 2;

    const int bg = blockIdx.x;
    const int c  = bg / CH;
    const int ch = bg % CH;
    const int b  = threadIdx.x & 63;
    const int w  = threadIdx.x >> 6;

    __shared__ __align__(16) char smem[NW * (DOUT + 1) * NB * 4];

    float V[DOUT];
    if (WEIGHTED) {
        const float* vb = vbuf + (size_t)c * DOUT * NB + b;
#pragma unroll
        for (int o = 0; o < DOUT; ++o) V[o] = vb[o * NB];
    }

    float S[DOUT];
#pragma unroll
    for (int o = 0; o < DOUT; ++o) S[o] = 0.f;
    float Z = 0.f;

    const int n0 = ch * NPC + w * NPW;
    const char* wsrc = (const char*)W + ((size_t)c * NCAP + n0) * 512;
    char* mybuf = smem + w * STG;

    auto STAGE = [&](int p) {
        __builtin_amdgcn_global_load_lds(
            (const AS1 void*)(wsrc + (size_t)p * 1024 + b * 16),
            (AS3 void*)(mybuf + (p & 3) * 1024), 16, 0, 0);
    };
    auto XROW = [&](int row, float4& xa, float4& xb) {
        const float4* xp = reinterpret_cast<const float4*>(
            xs + ((size_t)(n0 + row) * NB + b) * DIN);
        xa = xp[0];
        xb = xp[1];
    };
    auto ROW = [&](int p, int r, float4 xa, float4 xb) {
        const float4* wl = reinterpret_cast<const float4*>(mybuf + (p & 3) * 1024 + r * 512);
        const float xv[DIN] = {xa.x, xa.y, xa.z, xa.w, xb.x, xb.y, xb.z, xb.w};
        if (!WEIGHTED) {
#pragma unroll
            for (int i = 0; i < DIN; ++i) {
                float4 q0 = wl[i*4+0], q1 = wl[i*4+1], q2 = wl[i*4+2], q3 = wl[i*4+3];
                const float xi = xv[i];
                S[ 0]=fmaf(xi,q0.x,S[ 0]); S[ 1]=fmaf(xi,q0.y,S[ 1]);
                S[ 2]=fmaf(xi,q0.z,S[ 2]); S[ 3]=fmaf(xi,q0.w,S[ 3]);
                S[ 4]=fmaf(xi,q1.x,S[ 4]); S[ 5]=fmaf(xi,q1.y,S[ 5]);
                S[ 6]=fmaf(xi,q1.z,S[ 6]); S[ 7]=fmaf(xi,q1.w,S[ 7]);
                S[ 8]=fmaf(xi,q2.x,S[ 8]); S[ 9]=fmaf(xi,q2.y,S[ 9]);
                S[10]=fmaf(xi,q2.z,S[10]); S[11]=fmaf(xi,q2.w,S[11]);
                S[12]=fmaf(xi,q3.x,S[12]); S[13]=fmaf(xi,q3.y,S[13]);
                S[14]=fmaf(xi,q3.z,S[14]); S[15]=fmaf(xi,q3.w,S[15]);
            }
        } else {
            float u[DOUT];
#pragma unroll
            for (int o = 0; o < DOUT; ++o) u[o] = 0.f;
#pragma unroll
            for (int i = 0; i < DIN; ++i) {
                float4 q0 = wl[i*4+0], q1 = wl[i*4+1], q2 = wl[i*4+2], q3 = wl[i*4+3];
                const float xi = xv[i];
                u[ 0]=fmaf(xi,q0.x,u[ 0]); u[ 1]=fmaf(xi,q0.y,u[ 1]);
                u[ 2]=fmaf(xi,q0.z,u[ 2]); u[ 3]=fmaf(xi,q0.w,u[ 3]);
                u[ 4]=fmaf(xi,q1.x,u[ 4]); u[ 5]=fmaf(xi,q1.y,u[ 5]);
                u[ 6]=fmaf(xi,q1.z,u[ 6]); u[ 7]=fmaf(xi,q1.w,u[ 7]);
                u[ 8]=fmaf(xi,q2.x,u[ 8]); u[ 9]=fmaf(xi,q2.y,u[ 9]);
                u[10]=fmaf(xi,q2.z,u[10]); u[11]=fmaf(xi,q2.w,u[11]);
                u[12]=fmaf(xi,q3.x,u[12]); u[13]=fmaf(xi,q3.y,u[13]);
                u[14]=fmaf(xi,q3.z,u[14]); u[15]=fmaf(xi,q3.w,u[15]);
            }
            float bd = 0.f;
#pragma unroll
            for (int o = 0; o < DOUT; ++o) bd = fmaf(u[o], V[o], bd);
            const float g = __expf(bd);
            Z += g;
#pragma unroll
            for (int o = 0; o < DOUT; ++o) S[o] = fmaf(g, u[o], S[o]);
        }
    };

    STAGE(0); SB();
    STAGE(1); SB();
    float4 ca0, ca1, cb0, cb1, na0, na1, nb0, nb1;
    XROW(0, ca0, ca1);
    XROW(1, cb0, cb1);
    SB();

#pragma unroll 1
    for (int p = 0; p < NPAIRS; ++p) {
        if (p + 2 < NPAIRS) STAGE(p + 2);
        SB();
        if (p + 1 < NPAIRS) {
            XROW(2 * (p + 1),     na0, na1);
            XROW(2 * (p + 1) + 1, nb0, nb1);
        }
        SB();
        if (p < NPAIRS - 2)       { WAITV(5); }
        else if (p == NPAIRS - 2) { WAITV(4); }
        else                      { WAITV(0); }
        SB();
        ROW(p, 0, ca0, ca1);
        ROW(p, 1, cb0, cb1);
        ca0 = na0; ca1 = na1; cb0 = nb0; cb1 = nb1;
    }

    __syncthreads();
    float (*red)[DOUT + 1][NB] = reinterpret_cast<float (*)[DOUT + 1][NB]>(smem);
#pragma unroll
    for (int o = 0; o < DOUT; ++o) red[w][o][b] = S[o];
    red[w][DOUT][b] = Z;
    __syncthreads();
    for (int idx = threadIdx.x; idx < (DOUT + 1) * NB; idx += SWEEP_BLK) {
        const int slot = idx >> 6;
        const int bb   = idx & 63;
        float acc = 0.f;
#pragma unroll
        for (int k = 0; k < NW; ++k) acc += red[k][slot][bb];
        if (!WEIGHTED) {
            if (slot < DOUT)
                P[((size_t)bg * DOUT + slot) * NB + bb] = acc;
        } else {
            P[((size_t)bg * (DOUT + 1) + slot) * NB + bb] = acc;
        }
    }
}

template<int CH>
static void run_f32(const float* x, const float* W, float* out, float* ws,
                    hipStream_t stream) {
    using L = Layout<CH>;
    float* xs = ws + L::XS_OFF;
    float* P1 = ws + L::P1_OFF;
    float* P2 = ws + L::P2_OFF;
    float* P3 = ws + L::P3_OFF;
    float* VA = ws + L::VA_OFF;
    float* VB = ws + L::VB_OFF;

    hipLaunchKernelGGL(prep_kernel, dim3(NCAP * NB / 256), dim3(256), 0, stream, x, xs);
    hipLaunchKernelGGL((sweep_kernel<false, CH>), dim3(NCLS * CH), dim3(SWEEP_BLK), 0,
                       stream, xs, W, P1, nullptr);
    hipLaunchKernelGGL((vupd_kernel<1, CH>), dim3(NCLS), dim3(64), 0, stream,
                       P1, nullptr, VA);
    hipLaunchKernelGGL((sweep_kernel<true, CH>), dim3(NCLS * CH), dim3(SWEEP_BLK), 0,
                       stream, xs, W, P2, VA);
    hipLaunchKernelGGL((vupd_kernel<2, CH>), dim3(NCLS), dim3(64), 0, stream,
                       P2, VA, VB);
    hipLaunchKernelGGL((sweep_kernel<true, CH>), dim3(NCLS * CH), dim3(SWEEP_BLK), 0,
                       stream, xs, W, P3, VB);
    hipLaunchKernelGGL((final_kernel<CH>), dim3(NB), dim3(256), 0, stream, P3, out);
}

extern "C" void kernel_launch(void* const* d_in, const int* in_sizes, int n_in,
                              void* d_out, int out_size, void* d_ws, size_t ws_size,
                              hipStream_t stream) {
    const float* x = (const float*)d_in[0];
    const float* W = (const float*)d_in[1];
    float* out = (float*)d_out;
    float* ws  = (float*)d_ws;

    if (ws_size >= LM::TOTAL * sizeof(float)) {
        float* xsh = ws + LM::XSH_OFF;
        float* w2t = ws + LM::W2T_OFF;
        float* P1  = ws + LM::P1_OFF;
        float* P2  = ws + LM::P2_OFF;
        float* P3  = ws + LM::P3_OFF;
        float* VA  = ws + LM::VA_OFF;
        float* VB  = ws + LM::VB_OFF;

        hipLaunchKernelGGL(prep_x, dim3(NCAP * NB / 256), dim3(256), 0, stream, x, xsh);
        hipLaunchKernelGGL(prep_w2, dim3(NCLS * NCAP * DOUT / 256), dim3(256), 0, stream,
                           W, w2t);
        hipLaunchKernelGGL((sweep_m<false, CHM>), dim3(NCLS * CHM), dim3(256), 0,
                           stream, xsh, w2t, P1, nullptr);
        hipLaunchKernelGGL((vupd_kernel<1, CHM>), dim3(NCLS), dim3(64), 0, stream,
                           P1, nullptr, VA);
        hipLaunchKernelGGL((sweep_m<true, CHM>), dim3(NCLS * CHM), dim3(256), 0,
                           stream, xsh, w2t, P2, VA);
        hipLaunchKernelGGL((vupd_kernel<2, CHM>), dim3(NCLS), dim3(64), 0, stream,
                           P2, VA, VB);
        hipLaunchKernelGGL((sweep_m<true, CHM>), dim3(NCLS * CHM), dim3(256), 0,
                           stream, xsh, w2t, P3, VB);
        hipLaunchKernelGGL((final_kernel<CHM>), dim3(NB), dim3(256), 0, stream, P3, out);
    } else if (ws_size >= Layout<8>::TOTAL * sizeof(float)) {
        run_f32<8>(x, W, out, ws, stream);
    } else {
        run_f32<4>(x, W, out, ws, stream);
    }
}